// Round 17
// baseline (266.928 us; speedup 1.0000x reference)
//
#include <hip/hip_runtime.h>
#include <hip/hip_fp16.h>

#define N_NODES 100000
#define N_EDGES 1600000
#define BSHIFT 9
#define NBUCK ((N_NODES + 511) / 512)   // 196 coarse buckets of 512 nodes
#define BCAP 12288                      // per-bucket capacity (mean 8163, ~45 sigma)

// ---------------------------------------------------------------------------
// phase 1: bucket edges by dst>>9. Entry packed: src | (dst&511)<<17.
__global__ void bucket1_kernel(const int* __restrict__ src, const int* __restrict__ dst,
                               int* __restrict__ gbcount, int* __restrict__ bbuf, int E) {
    __shared__ int hcnt[NBUCK];
    __shared__ int hbase[NBUCK];
    int t = threadIdx.x;
    for (int i = t; i < NBUCK; i += 256) hcnt[i] = 0;
    __syncthreads();
    int e0 = blockIdx.x * 2048 + t;
    int ss[8], dd[8];
#pragma unroll
    for (int u = 0; u < 8; u++) {
        int e = e0 + u * 256;
        if (e < E) {
            ss[u] = src[e];
            dd[u] = dst[e];
            atomicAdd(&hcnt[dd[u] >> BSHIFT], 1);
        } else {
            dd[u] = -1;
        }
    }
    __syncthreads();
    for (int i = t; i < NBUCK; i += 256) {
        int c = hcnt[i];
        hbase[i] = c ? atomicAdd(&gbcount[i], c) : 0;
        hcnt[i] = 0;   // reuse as local cursor
    }
    __syncthreads();
#pragma unroll
    for (int u = 0; u < 8; u++) {
        if (dd[u] >= 0) {
            int bk = dd[u] >> BSHIFT;
            int r = atomicAdd(&hcnt[bk], 1);
            bbuf[(size_t)bk * BCAP + hbase[bk] + r] = ss[u] | ((dd[u] & 511) << 17);
        }
    }
}

// --- exclusive scan of the 196 bucket sizes -> bucket bases; rowptr[N]=E ----
__global__ void scan196_kernel(const int* __restrict__ gbcount, int* __restrict__ gbase,
                               int* __restrict__ rowptrN, int E) {
    __shared__ int s[256];
    int t = threadIdx.x;
    int v = (t < NBUCK) ? gbcount[t] : 0;
    s[t] = v;
    __syncthreads();
    for (int off = 1; off < 256; off <<= 1) {
        int u = (t >= off) ? s[t - off] : 0;
        __syncthreads();
        s[t] += u;
        __syncthreads();
    }
    if (t < NBUCK) gbase[t] = s[t] - v;
    if (t == 0) *rowptrN = E;
}

// --- phase 2 (fused hist+scan+dinv+scatter+PRESCALE): one 512-thr block/bucket.
// Tail prescales this bucket's x rows: x16[r] = fp16(dinv[r] * x[r])  — feeds
// the linearity-fused layer 1 (agg(dinv*x) @ W1 == agg(dinv*(x@W1))).
__global__ __launch_bounds__(512)
void bucket2_kernel(const int* __restrict__ bbuf, const int* __restrict__ gbcount,
                    const int* __restrict__ gbase, int* __restrict__ rowptr,
                    float* __restrict__ dinv, int* __restrict__ eidx,
                    const float* __restrict__ x, __half* __restrict__ x16, int N) {
    int b = blockIdx.x;
    int base_node = b << BSHIFT;
    int nn = min(512, N - base_node);
    int t = threadIdx.x;
    __shared__ int s[512];
    __shared__ int cur[512];
    __shared__ float sdinv[512];
    s[t] = 0;
    __syncthreads();
    int sz = gbcount[b];
    const int* eb = bbuf + (size_t)b * BCAP;
    for (int j = t; j < sz; j += 512) atomicAdd(&s[((unsigned)eb[j]) >> 17], 1);
    __syncthreads();
    int myc = s[t];
    float dv = rsqrtf((float)myc + 1.0f);
    sdinv[t] = dv;
    if (t < nn) dinv[base_node + t] = dv;
    __syncthreads();
    for (int off = 1; off < 512; off <<= 1) {
        int u = (t >= off) ? s[t - off] : 0;
        __syncthreads();
        s[t] += u;
        __syncthreads();
    }
    int rp = gbase[b] + s[t] - myc;      // exclusive
    if (t < nn) rowptr[base_node + t] = rp;
    cur[t] = rp;
    __syncthreads();
    for (int j = t; j < sz; j += 512) {
        int e = eb[j];
        int pos = atomicAdd(&cur[((unsigned)e) >> 17], 1);
        eidx[pos] = e & 0x1FFFF;
    }
    // --- prescale tail: 16 float4 per row (64 feats), fp16(dinv*x) ---
    for (int i = t; i < nn * 16; i += 512) {
        int r = i >> 4, c = i & 15;
        float4 v = ((const float4*)x)[((size_t)(base_node + r)) * 16 + c];
        float d = sdinv[r];
        union { __half h[4]; uint2 u; } pk;
        pk.h[0] = __float2half_rn(d * v.x);
        pk.h[1] = __float2half_rn(d * v.y);
        pk.h[2] = __float2half_rn(d * v.z);
        pk.h[3] = __float2half_rn(d * v.w);
        *(uint2*)&x16[((size_t)(base_node + r)) * 64 + c * 4] = pk.u;
    }
}

// --- determinism: canonicalize each row (sort ascending). One WAVE per row. --
__global__ void sortrow_wave(const int* __restrict__ rowptr, int* __restrict__ eidx, int n) {
    int g = (blockIdx.x * blockDim.x + threadIdx.x) >> 6;
    int lane = threadIdx.x & 63;
    if (g >= n) return;
    int start = rowptr[g];
    int end = rowptr[g + 1];
    int len = end - start;
    if (len <= 1) return;

    if (len <= 64) {
        int v = (lane < len) ? eidx[start + lane] : 0x7fffffff;
#pragma unroll
        for (int k = 2; k <= 64; k <<= 1) {
#pragma unroll
            for (int j = k >> 1; j > 0; j >>= 1) {
                int partner = __shfl_xor(v, j, 64);
                bool up = ((lane & k) == 0);
                bool keepMin = (((lane & j) == 0) == up);
                int mn = min(v, partner), mx = max(v, partner);
                v = keepMin ? mn : mx;
            }
        }
        if (lane < len) eidx[start + lane] = v;
    } else if (lane == 0) {
        for (int i = start + 1; i < end; i++) {
            int key = eidx[i];
            int j = i - 1;
            while (j >= start && eidx[j] > key) { eidx[j + 1] = eidx[j]; j--; }
            eidx[j + 1] = key;
        }
    }
}

// ---------------------------------------------------------------------------
// FUSED layer 1+2 front: gather x16 -> u = agg+self (fp32),
//   v  = relu( di * (u @ W1) + b1 )            [64]
//   A2 = fp16( di * (v @ W2) )                 [32]   (prescaled for layer-2 gather)
// 8 lanes/node, 32 nodes/block. su stride 65 (bank-conflict pad, R14/15 lesson).
// LDS: sW1 16K + sW2 8K + su 8.3K = 33 KB -> 4 blocks/CU. (256,4): no spill.
__global__ __launch_bounds__(256, 4)
void agg_gemm2x_kernel(const int* __restrict__ eidx, const int* __restrict__ rowptr,
                       const float* __restrict__ dinv, const __half* __restrict__ h,
                       const float* __restrict__ b1, const float* __restrict__ W1,
                       const float* __restrict__ W2, __half* __restrict__ outA2, int n) {
    constexpr int L = 8;
    constexpr int PH = 8;                // halves per lane (64/8)
    constexpr int NODES = 32;
    constexpr int SVS = 65;
    using vh = _Float16 __attribute__((ext_vector_type(8)));
    __shared__ float sW1[64 * 64];
    __shared__ float sW2[64 * 32];
    __shared__ float su[NODES * SVS];

    for (int i = threadIdx.x; i < 64 * 64 / 4; i += 256)
        ((float4*)sW1)[i] = ((const float4*)W1)[i];
    for (int i = threadIdx.x; i < 64 * 32 / 4; i += 256)
        ((float4*)sW2)[i] = ((const float4*)W2)[i];

    int g = (blockIdx.x * blockDim.x + threadIdx.x) / L;
    int lane = threadIdx.x % L;
    int slot = threadIdx.x / L;
    float di = 0.f;

    if (g < n) {
        int j = rowptr[g];
        int end = rowptr[g + 1];
        di = dinv[g];
        const __half* hb = h + lane * PH;

        float acc0[PH], acc1[PH];
#pragma unroll
        for (int q = 0; q < PH; q++) { acc0[q] = 0.f; acc1[q] = 0.f; }

        for (; j + 8 <= end; j += 8) {
            int s0 = eidx[j];
            int s1 = eidx[j + 1];
            int s2 = eidx[j + 2];
            int s3 = eidx[j + 3];
            int s4 = eidx[j + 4];
            int s5 = eidx[j + 5];
            int s6 = eidx[j + 6];
            int s7 = eidx[j + 7];
            vh v0 = *(const vh*)(hb + (size_t)s0 * 64);
            vh v1 = *(const vh*)(hb + (size_t)s1 * 64);
            vh v2 = *(const vh*)(hb + (size_t)s2 * 64);
            vh v3 = *(const vh*)(hb + (size_t)s3 * 64);
            vh v4 = *(const vh*)(hb + (size_t)s4 * 64);
            vh v5 = *(const vh*)(hb + (size_t)s5 * 64);
            vh v6 = *(const vh*)(hb + (size_t)s6 * 64);
            vh v7 = *(const vh*)(hb + (size_t)s7 * 64);
#pragma unroll
            for (int q = 0; q < PH; q++) {
                acc0[q] += (float)v0[q] + (float)v2[q];
                acc1[q] += (float)v1[q] + (float)v3[q];
                acc0[q] += (float)v4[q] + (float)v6[q];
                acc1[q] += (float)v5[q] + (float)v7[q];
            }
        }
        for (; j + 2 <= end; j += 2) {
            int s0 = eidx[j];
            int s1 = eidx[j + 1];
            vh v0 = *(const vh*)(hb + (size_t)s0 * 64);
            vh v1 = *(const vh*)(hb + (size_t)s1 * 64);
#pragma unroll
            for (int q = 0; q < PH; q++) { acc0[q] += (float)v0[q]; acc1[q] += (float)v1[q]; }
        }
        if (j < end) {
            vh v = *(const vh*)(hb + (size_t)eidx[j] * 64);
#pragma unroll
            for (int q = 0; q < PH; q++) acc0[q] += (float)v[q];
        }

        vh sf = *(const vh*)(hb + (size_t)g * 64);
        float* sun = &su[slot * SVS + lane * PH];
#pragma unroll
        for (int q = 0; q < PH; q++)
            sun[q] = (acc0[q] + acc1[q]) + (float)sf[q];   // u (incl. self)
    }
    __syncthreads();                     // sW1/sW2 loaded + su(u) written

    // matvec 1: v = relu(di * (u @ W1) + b1); lane owns 8 cols
    float v8[8] = {};
    if (g < n) {
        const float* un = &su[slot * SVS];
        for (int k = 0; k < 64; k++) {
            float uk = un[k];
            float4 wa = *(const float4*)&sW1[k * 64 + lane * 8];
            float4 wb = *(const float4*)&sW1[k * 64 + lane * 8 + 4];
            v8[0] += uk * wa.x; v8[1] += uk * wa.y; v8[2] += uk * wa.z; v8[3] += uk * wa.w;
            v8[4] += uk * wb.x; v8[5] += uk * wb.y; v8[6] += uk * wb.z; v8[7] += uk * wb.w;
        }
#pragma unroll
        for (int q = 0; q < 8; q++) v8[q] = fmaxf(di * v8[q] + b1[lane * 8 + q], 0.f);
    }
    __syncthreads();                     // all reads of u done
    if (g < n) {
        float* sun = &su[slot * SVS + lane * 8];
#pragma unroll
        for (int q = 0; q < 8; q++) sun[q] = v8[q];        // overwrite u with v
    }
    __syncthreads();

    // matvec 2: A2 = fp16(di * (v @ W2)); lane owns 4 cols
    if (g < n) {
        const float* vn = &su[slot * SVS];
        float o[4] = {};
        for (int k = 0; k < 64; k++) {
            float vk = vn[k];
            float4 w = *(const float4*)&sW2[k * 32 + lane * 4];
            o[0] += vk * w.x; o[1] += vk * w.y; o[2] += vk * w.z; o[3] += vk * w.w;
        }
        union { __half h[4]; uint2 u; } pk;
#pragma unroll
        for (int q = 0; q < 4; q++) pk.h[q] = __float2half_rn(di * o[q]);
        *(uint2*)&outA2[(size_t)g * 32 + lane * 4] = pk.u;
    }
}

// ---------------------------------------------------------------------------
// FUSED aggregation + next-layer matvec (layer 2->3). SVS pad, (256,4): R16 cfg.
template <int FIN, int FOUT, bool OUT_HALF>
__global__ __launch_bounds__(256, 4)
void agg_gemm_kernel(const int* __restrict__ eidx, const int* __restrict__ rowptr,
                     const float* __restrict__ dinv, const __half* __restrict__ h,
                     const float* __restrict__ bias, const float* __restrict__ W,
                     void* __restrict__ outv, int n) {
    constexpr int L = 8;
    constexpr int PH = FIN / L;
    constexpr int NODES = 256 / L;
    constexpr int SVS = FIN + 1;
    using vh = _Float16 __attribute__((ext_vector_type(PH)));
    __shared__ float sW[FIN * FOUT];
    __shared__ float sv[NODES * SVS];

    for (int i = threadIdx.x; i < FIN * FOUT / 4; i += 256)
        ((float4*)sW)[i] = ((const float4*)W)[i];

    int g = (blockIdx.x * blockDim.x + threadIdx.x) / L;
    int lane = threadIdx.x % L;
    int slot = threadIdx.x / L;
    float di = 0.f;

    if (g < n) {
        int j = rowptr[g];
        int end = rowptr[g + 1];
        di = dinv[g];
        const __half* hb = h + lane * PH;

        float acc0[PH], acc1[PH];
#pragma unroll
        for (int q = 0; q < PH; q++) { acc0[q] = 0.f; acc1[q] = 0.f; }

        for (; j + 8 <= end; j += 8) {
            int s0 = eidx[j];
            int s1 = eidx[j + 1];
            int s2 = eidx[j + 2];
            int s3 = eidx[j + 3];
            int s4 = eidx[j + 4];
            int s5 = eidx[j + 5];
            int s6 = eidx[j + 6];
            int s7 = eidx[j + 7];
            vh v0 = *(const vh*)(hb + (size_t)s0 * FIN);
            vh v1 = *(const vh*)(hb + (size_t)s1 * FIN);
            vh v2 = *(const vh*)(hb + (size_t)s2 * FIN);
            vh v3 = *(const vh*)(hb + (size_t)s3 * FIN);
            vh v4 = *(const vh*)(hb + (size_t)s4 * FIN);
            vh v5 = *(const vh*)(hb + (size_t)s5 * FIN);
            vh v6 = *(const vh*)(hb + (size_t)s6 * FIN);
            vh v7 = *(const vh*)(hb + (size_t)s7 * FIN);
#pragma unroll
            for (int q = 0; q < PH; q++) {
                acc0[q] += (float)v0[q] + (float)v2[q];
                acc1[q] += (float)v1[q] + (float)v3[q];
                acc0[q] += (float)v4[q] + (float)v6[q];
                acc1[q] += (float)v5[q] + (float)v7[q];
            }
        }
        for (; j + 2 <= end; j += 2) {
            int s0 = eidx[j];
            int s1 = eidx[j + 1];
            vh v0 = *(const vh*)(hb + (size_t)s0 * FIN);
            vh v1 = *(const vh*)(hb + (size_t)s1 * FIN);
#pragma unroll
            for (int q = 0; q < PH; q++) { acc0[q] += (float)v0[q]; acc1[q] += (float)v1[q]; }
        }
        if (j < end) {
            vh v = *(const vh*)(hb + (size_t)eidx[j] * FIN);
#pragma unroll
            for (int q = 0; q < PH; q++) acc0[q] += (float)v[q];
        }

        vh sf = *(const vh*)(hb + (size_t)g * FIN);
        float* svn = &sv[slot * SVS + lane * PH];
#pragma unroll
        for (int q = 0; q < PH; q++) {
            float v = di * ((acc0[q] + acc1[q]) + (float)sf[q]) + bias[lane * PH + q];
            svn[q] = fmaxf(v, 0.f);      // relu
        }
    }
    __syncthreads();

    if (g < n) {
        const float* vn = &sv[slot * SVS];
        if constexpr (OUT_HALF) {
            constexpr int PC = FOUT / L;
            float o[PC] = {};
            for (int k = 0; k < FIN; k++) {
                float vk = vn[k];
                float4 w = *(const float4*)&sW[k * FOUT + lane * PC];
                o[0] += vk * w.x; o[1] += vk * w.y; o[2] += vk * w.z; o[3] += vk * w.w;
            }
            union { __half h[4]; uint2 u; } pk;
#pragma unroll
            for (int q = 0; q < PC; q++) pk.h[q] = __float2half_rn(di * o[q]);
            *(uint2*)((__half*)outv + (size_t)g * FOUT + lane * PC) = pk.u;
        } else {
            if (lane < FOUT) {
                float o = 0.f;
                for (int k = 0; k < FIN; k++) o += vn[k] * sW[k * FOUT + lane];
                ((float*)outv)[(size_t)g * FOUT + lane] = di * o;
            }
        }
    }
}

// fp32 scalar-gather agg for the final layer (F=2), bias, no relu
template <int F>
__global__ void agg_kernel(const int* __restrict__ eidx, const int* __restrict__ rowptr,
                           const float* __restrict__ dinv, const float* __restrict__ h,
                           const float* __restrict__ b, float* __restrict__ out, int n) {
    int g = (blockIdx.x * blockDim.x + threadIdx.x) / F;
    int lane = threadIdx.x % F;
    if (g >= n) return;
    int j = rowptr[g];
    int end = rowptr[g + 1];
    float di = dinv[g];
    float hs = h[(size_t)g * F + lane];

    float acc0 = 0.f, acc1 = 0.f, acc2 = 0.f, acc3 = 0.f;
    float acc4 = 0.f, acc5 = 0.f, acc6 = 0.f, acc7 = 0.f;
    for (; j + 8 <= end; j += 8) {
        int s0 = eidx[j];
        int s1 = eidx[j + 1];
        int s2 = eidx[j + 2];
        int s3 = eidx[j + 3];
        int s4 = eidx[j + 4];
        int s5 = eidx[j + 5];
        int s6 = eidx[j + 6];
        int s7 = eidx[j + 7];
        acc0 += h[(size_t)s0 * F + lane];
        acc1 += h[(size_t)s1 * F + lane];
        acc2 += h[(size_t)s2 * F + lane];
        acc3 += h[(size_t)s3 * F + lane];
        acc4 += h[(size_t)s4 * F + lane];
        acc5 += h[(size_t)s5 * F + lane];
        acc6 += h[(size_t)s6 * F + lane];
        acc7 += h[(size_t)s7 * F + lane];
    }
    for (; j + 2 <= end; j += 2) {
        int s0 = eidx[j];
        int s1 = eidx[j + 1];
        acc0 += h[(size_t)s0 * F + lane];
        acc1 += h[(size_t)s1 * F + lane];
    }
    if (j < end) {
        acc2 += h[(size_t)eidx[j] * F + lane];
    }
    float acc = ((acc0 + acc1) + (acc2 + acc3)) + ((acc4 + acc5) + (acc6 + acc7));
    out[(size_t)g * F + lane] = di * (acc + hs) + b[lane];
}

// ---------------------------------------------------------------------------
extern "C" void kernel_launch(void* const* d_in, const int* in_sizes, int n_in,
                              void* d_out, int out_size, void* d_ws, size_t ws_size,
                              hipStream_t stream) {
    const float* x  = (const float*)d_in[0];
    const int* ei   = (const int*)d_in[1];
    const float* W1 = (const float*)d_in[2];
    const float* b1 = (const float*)d_in[3];
    const float* W2 = (const float*)d_in[4];
    const float* b2 = (const float*)d_in[5];
    const float* W3 = (const float*)d_in[6];
    const float* b3 = (const float*)d_in[7];
    float* out = (float*)d_out;

    const int N = N_NODES;
    const int E = N_EDGES;
    const int* src = ei;
    const int* dst = ei + E;

    char* p = (char*)d_ws;
    int*    rowptr  = (int*)p;            p += ((size_t)(N + 1) * 4 + 15) / 16 * 16;
    float*  dinv    = (float*)p;          p += ((size_t)N * 4 + 15) / 16 * 16;
    int*    gbcount = (int*)p;            p += ((size_t)NBUCK * 4 + 15) / 16 * 16;
    int*    gbase   = (int*)p;            p += ((size_t)NBUCK * 4 + 15) / 16 * 16;
    int*    eidx    = (int*)p;            p += (size_t)E * 4;
    __half* x16     = (__half*)p;         p += (size_t)N * 64 * 2;   // dinv-prescaled x
    __half* A2      = (__half*)p;         p += (size_t)N * 32 * 2;
    float*  A3      = (float*)p;          p += (size_t)N * 2 * 4;
    int*    bbuf    = (int*)p;            // 196*12288*4 = 9.6 MB (packed edges)

    const int T = 256;

    // --- build CSR + dinv + prescale: bucket -> scan196 -> bucket2 ; sort ---
    hipMemsetAsync(gbcount, 0, NBUCK * sizeof(int), stream);
    bucket1_kernel<<<(E + 2047) / 2048, T, 0, stream>>>(src, dst, gbcount, bbuf, E);
    scan196_kernel<<<1, 256, 0, stream>>>(gbcount, gbase, rowptr + N, E);
    bucket2_kernel<<<NBUCK, 512, 0, stream>>>(bbuf, gbcount, gbase, rowptr, dinv, eidx,
                                              x, x16, N);
    sortrow_wave<<<(N * 64 + T - 1) / T, T, 0, stream>>>(rowptr, eidx, N);

    // --- fused layer1+2 front: gather x16, u=agg; v=relu(di*uW1+b1); A2=fp16(di*vW2) ---
    agg_gemm2x_kernel<<<(N + 31) / 32, T, 0, stream>>>(
        eidx, rowptr, dinv, x16, b1, W1, W2, A2, N);

    // --- fused agg2 + gemm3: A3 = fp32(di * relu(agg(A2)+b2) @ W3) ---
    agg_gemm_kernel<32, 2, false><<<(N + 31) / 32, T, 0, stream>>>(
        eidx, rowptr, dinv, A2, b2, W3, A3, N);

    // --- final aggregation: out = di*(agg(A3)+self) + b3 ---
    agg_kernel<2><<<(N * 2 + T - 1) / T, T, 0, stream>>>(eidx, rowptr, dinv, A3, b3, out, N);
}